// Round 9
// baseline (208.030 us; speedup 1.0000x reference)
//
#include <hip/hip_runtime.h>
#include <hip/hip_cooperative_groups.h>

namespace cg = cooperative_groups;

// Problem constants
#define B_ 16
#define C_ 512
#define H_ 28
#define W_ 28
#define TPREV 15
#define TT 16          // TPREV + 1
#define HEADS_ 16
#define DHEAD 32       // C_/HEADS_
#define HW 784         // H_*W_
#define HW4 196        // HW/4
#define CH4 (C_ * HW4) // quads per (b,t) slab = 100352
#define NORM 0.17677669529663687f  // 1/sqrt(32)

#define POOL_UNITS (B_ * C_)                // 8192 channel-mean units (one wave each)
#define KCOPY_QUADS (B_ * TPREV * C_ / 4)   // 30720 f32x4 quads of prev_K
#define NUNITS (B_ * C_ * HW4 / 256)        // 6272 streaming units of 256 quads

typedef float f32x4 __attribute__((ext_vector_type(4)));  // native vector for nontemporal builtins

// ---- single cooperative kernel: pool + kcopy | grid.sync | att + conv + V concat + PV ----
__global__ __launch_bounds__(256) void mega_kernel(const float* __restrict__ x,
                                                   const float* __restrict__ prevK,
                                                   const float* __restrict__ prevV,
                                                   const float* __restrict__ wq,
                                                   const float* __restrict__ wk,
                                                   const float* __restrict__ wv,
                                                   float* __restrict__ out,
                                                   float* __restrict__ Kout,
                                                   float* __restrict__ Vout,
                                                   float* __restrict__ y) {
    const int tid = threadIdx.x;
    const int nb  = gridDim.x;
    __shared__ float att_s[3][TT];

    // ================= phase 1a: global average pool (one 64-lane wave per channel) ==========
    {
        const int lane   = tid & 63;
        const int nwaves = nb * 4;
        for (int u = blockIdx.x * 4 + (tid >> 6); u < POOL_UNITS; u += nwaves) {
            const f32x4* __restrict__ xr = (const f32x4*)(x + (size_t)u * HW);
            float s = 0.0f;
            for (int i = lane; i < HW4; i += 64) {
                f32x4 v = xr[i];
                s += v.x + v.y + v.z + v.w;
            }
            #pragma unroll
            for (int off = 32; off > 0; off >>= 1) s += __shfl_down(s, off);
            if (lane == 0) y[u] = s * (1.0f / (float)HW);
        }
    }
    // ================= phase 1b: prev_K -> Kout copy (skip t=15 slot per batch) ==============
    {
        const int nthr = nb * 256;
        const f32x4* __restrict__ src = (const f32x4*)prevK;
        f32x4* __restrict__ dst = (f32x4*)Kout;
        for (int j = blockIdx.x * 256 + tid; j < KCOPY_QUADS; j += nthr) {
            const int b = j / (TPREV * C_ / 4);       // / 1920
            dst[j + b * (C_ / 4)] = src[j];
        }
    }

    cg::this_grid().sync();

    // ================= phase 2: streaming units (round-8 proven body) ========================
    for (int u = blockIdx.x; u < NUNITS; u += nb) {
        const int blk0  = u * 256;                    // first flat quad of unit
        const int bc_lo = blk0 / HW4;
        const int bc_hi = (blk0 + 255) / HW4;         // bc_lo, +1, or +2

        __syncthreads();                              // prev iteration done reading att_s

        // ---- att phase: lanes 0..95 (3 half-groups of 32, one per spanned channel) ----
        if (tid < 96) {
            const int half = tid >> 5;
            const int d    = tid & 31;
            const int bcx  = bc_lo + half;
            if (bcx <= bc_hi) {
                const int bb = bcx >> 9;
                const int gg = (bcx & (C_ - 1)) >> 5;
                const int cc = gg * DHEAD + d;

                float Qc = 0.0f, kc = 0.0f;
                #pragma unroll
                for (int j = 0; j < 5; ++j) {
                    const int cj = cc - 2 + j;
                    const float yv = (cj >= 0 && cj < C_) ? y[bb * C_ + cj] : 0.0f;
                    Qc = fmaf(yv, wq[j], Qc);
                    kc = fmaf(yv, wk[j], kc);
                }

                float pl[TT];
                #pragma unroll
                for (int t = 0; t < TPREV; ++t)
                    pl[t] = Qc * prevK[((size_t)bb * TPREV + t) * C_ + cc];
                pl[TPREV] = Qc * kc;

                #pragma unroll
                for (int m = 1; m <= 16; m <<= 1) {
                    #pragma unroll
                    for (int t = 0; t < TT; ++t)
                        pl[t] += __shfl_xor(pl[t], m);
                }

                float mx = -1e30f;
                #pragma unroll
                for (int t = 0; t < TT; ++t) mx = fmaxf(mx, pl[t] * NORM);
                float sum = 0.0f;
                #pragma unroll
                for (int t = 0; t < TT; ++t) sum += __expf(pl[t] * NORM - mx);
                if (d < TT)
                    att_s[half][d] = __expf(pl[d] * NORM - mx) / sum;

                // Kout[b,15,cc]: unique unit containing quad (bb*C_+cc)*HW4 writes it
                const int qk = (bb * C_ + cc) * HW4;
                if (qk >= blk0 && qk < blk0 + 256)
                    Kout[((size_t)bb * TT + TPREV) * C_ + cc] = kc;
            }
        }
        __syncthreads();

        // ---- streaming: burst 15 NT loads, conv under latency, store-through + FMA drain ----
        const int i  = blk0 + tid;
        const int p4 = i % HW4;
        const int bc = i / HW4;
        const int c  = bc & (C_ - 1);
        const int b  = bc >> 9;
        const int h_ = bc - bc_lo;                    // 0..2: which att row

        f32x4* __restrict__ Vo = (f32x4*)Vout;
        const f32x4* __restrict__ Pv = (const f32x4*)prevV;
        const size_t pvq = ((size_t)b * TPREV * C_ + c) * HW4 + p4;
        const size_t voq = ((size_t)b * TT    * C_ + c) * HW4 + p4;

        f32x4 pv[TPREV];
        #pragma unroll
        for (int t = 0; t < TPREV; ++t)
            pv[t] = __builtin_nontemporal_load(&Pv[pvq + (size_t)t * CH4]);

        const float* __restrict__ xbc = x + (size_t)bc * HW;
        const int p  = p4 * 4;
        const int h  = p / W_;
        const int w0 = p % W_;
        float r[3][6];
        #pragma unroll
        for (int ry = 0; ry < 3; ++ry) {
            const int hh = h - 1 + ry;
            if (hh < 0 || hh >= H_) {
                #pragma unroll
                for (int j = 0; j < 6; ++j) r[ry][j] = 0.0f;
            } else {
                const float* row = xbc + hh * W_;
                f32x4 mid = *(const f32x4*)(row + w0);
                r[ry][1] = mid.x; r[ry][2] = mid.y; r[ry][3] = mid.z; r[ry][4] = mid.w;
                r[ry][0] = (w0 > 0)      ? row[w0 - 1] : 0.0f;
                r[ry][5] = (w0 + 4 < W_) ? row[w0 + 4] : 0.0f;
            }
        }
        float wv9[9];
        #pragma unroll
        for (int k = 0; k < 9; ++k) wv9[k] = wv[c * 9 + k];

        f32x4 v4;
        #pragma unroll
        for (int j = 0; j < 4; ++j) {
            float s = 0.0f;
            #pragma unroll
            for (int ky = 0; ky < 3; ++ky)
                #pragma unroll
                for (int kx = 0; kx < 3; ++kx)
                    s = fmaf(r[ky][j + kx], wv9[ky * 3 + kx], s);
            v4[j] = s;
        }

        f32x4 acc;
        {
            const float a = att_s[h_][TPREV];
            __builtin_nontemporal_store(v4, &Vo[voq + (size_t)TPREV * CH4]);
            acc = v4 * a;
        }

        #pragma unroll
        for (int t = 0; t < TPREV; ++t) {
            __builtin_nontemporal_store(pv[t], &Vo[voq + (size_t)t * CH4]);
            const float a = att_s[h_][t];
            acc.x = fmaf(a, pv[t].x, acc.x);
            acc.y = fmaf(a, pv[t].y, acc.y);
            acc.z = fmaf(a, pv[t].z, acc.z);
            acc.w = fmaf(a, pv[t].w, acc.w);
        }
        __builtin_nontemporal_store(acc, &((f32x4*)out)[(size_t)bc * HW4 + p4]);
    }
}

extern "C" void kernel_launch(void* const* d_in, const int* in_sizes, int n_in,
                              void* d_out, int out_size, void* d_ws, size_t ws_size,
                              hipStream_t stream) {
    const float* x     = (const float*)d_in[0];
    const float* prevK = (const float*)d_in[1];
    const float* prevV = (const float*)d_in[2];
    const float* wq    = (const float*)d_in[3];
    const float* wk    = (const float*)d_in[4];
    const float* wv    = (const float*)d_in[5];

    float* out  = (float*)d_out;                       // [B,C,H,W]
    float* Kout = out + (size_t)B_ * C_ * HW;          // [B,TT,C]
    float* Vout = Kout + (size_t)B_ * TT * C_;         // [B,TT,C,H,W]

    float* y_ws = (float*)d_ws;                        // B*C pooled means

    // co-residency-safe grid: 896 divides NUNITS (6272 = 896*7); clamp by occupancy
    int occ = 0;
    (void)hipOccupancyMaxActiveBlocksPerMultiprocessor(&occ, mega_kernel, 256, 0);
    if (occ < 1) occ = 1;
    int grid = occ * 256;                              // 256 CUs on MI355X
    if (grid > 896) grid = 896;

    void* args[] = {(void*)&x, (void*)&prevK, (void*)&prevV, (void*)&wq, (void*)&wk,
                    (void*)&wv, (void*)&out, (void*)&Kout, (void*)&Vout, (void*)&y_ws};
    (void)hipLaunchCooperativeKernel((void*)mega_kernel, dim3(grid), dim3(256),
                                     args, 0, stream);
}

// Round 10
// 160.219 us; speedup vs baseline: 1.2984x; 1.2984x over previous
//
#include <hip/hip_runtime.h>
#include <hip/hip_bf16.h>

// Problem constants
#define B_ 16
#define C_ 512
#define H_ 28
#define W_ 28
#define TPREV 15
#define TT 16          // TPREV + 1
#define HEADS_ 16
#define DHEAD 32       // C_/HEADS_
#define HW 784         // H_*W_
#define HW4 196        // HW/4
#define CH4 (C_ * HW4) // quads per (b,t) slab = 100352
#define NORM 0.17677669529663687f  // 1/sqrt(32)

typedef float f32x4 __attribute__((ext_vector_type(4)));  // native vector for nontemporal builtins

#define POOL_BLOCKS (B_ * C_)               // 8192 blocks of 64 threads, one per (b,c)
#define KCOPY_QUADS (B_ * TPREV * C_ / 4)   // 30720 f32x4 quads of prev_K
#define KCOPY_BLOCKS (KCOPY_QUADS / 64)     // 480

// ---------------- Kernel 1: global average pool + prev_K -> Kout copy ----------------
__global__ __launch_bounds__(64) void pool_copy_kernel(const float* __restrict__ x,
                                                       const float* __restrict__ prevK,
                                                       float* __restrict__ y,
                                                       float* __restrict__ Kout) {
    const int lane = threadIdx.x;
    if (blockIdx.x < POOL_BLOCKS) {
        const int bc = blockIdx.x;                    // 0..B*C-1
        const f32x4* __restrict__ xr = (const f32x4*)(x + (size_t)bc * HW);
        float s = 0.0f;
        for (int i = lane; i < HW4; i += 64) {
            f32x4 v = xr[i];
            s += v.x + v.y + v.z + v.w;
        }
        #pragma unroll
        for (int off = 32; off > 0; off >>= 1) s += __shfl_down(s, off);
        if (lane == 0) y[bc] = s * (1.0f / (float)HW);
    } else {
        // copy prev_K [B,15,C] into Kout [B,16,C] (t<15 region), quad-wise
        const int j = (blockIdx.x - POOL_BLOCKS) * 64 + lane;   // 0..30719
        const f32x4* __restrict__ src = (const f32x4*)prevK;
        f32x4* __restrict__ dst = (f32x4*)Kout;
        const int b = j / (TPREV * C_ / 4);           // / 1920
        dst[j + b * (C_ / 4)] = src[j];               // skip the t=15 slot per batch
    }
}

// ---------------- Kernel 2: fused att-compute + depthwise conv + V concat + PV ----------------
// A 256-quad block spans up to THREE (b,c) channels (196 quads/channel, 256 > 196).
// Lanes 0..95 (3 half-groups of 32) recompute the att rows for channels bc_lo..bc_lo+2
// from y/prev_K/wq/wk (tiny, cached), plus write Kout[b,15,:] for owned channels.
__global__ __launch_bounds__(256) void fuse_kernel(const float* __restrict__ x,
                                                   const float* __restrict__ prevV,
                                                   const float* __restrict__ prevK,
                                                   const float* __restrict__ y,
                                                   const float* __restrict__ wq,
                                                   const float* __restrict__ wk,
                                                   const float* __restrict__ wv,
                                                   float* __restrict__ out,
                                                   float* __restrict__ Kout,
                                                   float* __restrict__ Vout) {
    const int tid = threadIdx.x;
    const int blk0 = blockIdx.x * 256;                // first flat quad of block
    __shared__ float att_s[3][TT];

    const int bc_lo = blk0 / HW4;
    const int bc_hi = (blk0 + 255) / HW4;             // bc_lo, +1, or +2

    // ---- att phase: lanes 0..95 ----
    if (tid < 96) {
        const int half = tid >> 5;                    // 0..2: which spanned channel
        const int d    = tid & 31;
        const int bcx  = bc_lo + half;
        if (bcx <= bc_hi) {                           // also guards bcx < B_*C_
            const int bb = bcx >> 9;
            const int gg = (bcx & (C_ - 1)) >> 5;
            const int cc = gg * DHEAD + d;

            // conv1d (SAME, zero pad) for Q and k at channel cc
            float Qc = 0.0f, kc = 0.0f;
            #pragma unroll
            for (int j = 0; j < 5; ++j) {
                const int cj = cc - 2 + j;
                const float yv = (cj >= 0 && cj < C_) ? y[bb * C_ + cj] : 0.0f;
                Qc = fmaf(yv, wq[j], Qc);
                kc = fmaf(yv, wk[j], kc);
            }

            // per-lane logit partials over t
            float pl[TT];
            #pragma unroll
            for (int t = 0; t < TPREV; ++t)
                pl[t] = Qc * prevK[((size_t)bb * TPREV + t) * C_ + cc];
            pl[TPREV] = Qc * kc;

            // butterfly reduce across the 32-lane half (xor masks stay within the half)
            #pragma unroll
            for (int m = 1; m <= 16; m <<= 1) {
                #pragma unroll
                for (int t = 0; t < TT; ++t)
                    pl[t] += __shfl_xor(pl[t], m);
            }

            // softmax (every lane has all 16 sums; redundant identical fp32 math)
            float mx = -1e30f;
            #pragma unroll
            for (int t = 0; t < TT; ++t) mx = fmaxf(mx, pl[t] * NORM);
            float sum = 0.0f;
            #pragma unroll
            for (int t = 0; t < TT; ++t) sum += __expf(pl[t] * NORM - mx);
            if (d < TT)
                att_s[half][d] = __expf(pl[d] * NORM - mx) / sum;

            // Kout[b,15,cc]: written by the unique block containing quad (bb*C_+cc)*HW4
            // (duplicate writers across halves carry identical values — benign)
            const int qk = (bb * C_ + cc) * HW4;
            if (qk >= blk0 && qk < blk0 + 256)
                Kout[((size_t)bb * TT + TPREV) * C_ + cc] = kc;
        }
    }
    __syncthreads();

    // ---- streaming phase (proven round-6 pattern) ----
    const int i  = blk0 + tid;                        // flat quad index
    const int p4 = i % HW4;
    const int bc = i / HW4;
    const int c  = bc & (C_ - 1);
    const int b  = bc >> 9;
    const int h_ = bc - bc_lo;                        // 0..2: which att row

    f32x4* __restrict__ Vo = (f32x4*)Vout;
    const f32x4* __restrict__ Pv = (const f32x4*)prevV;
    const size_t pvq = ((size_t)b * TPREV * C_ + c) * HW4 + p4;  // prevV quad @ t=0
    const size_t voq = ((size_t)b * TT    * C_ + c) * HW4 + p4;  // Vout  quad @ t=0

    // burst: issue all 15 prev_V NT loads first (15 KB/wave in flight)
    f32x4 pv[TPREV];
    #pragma unroll
    for (int t = 0; t < TPREV; ++t)
        pv[t] = __builtin_nontemporal_load(&Pv[pvq + (size_t)t * CH4]);

    // depthwise 3x3 conv (SAME, zero pad) for 4 consecutive pixels — overlaps load latency
    const float* __restrict__ xbc = x + (size_t)bc * HW;
    const int p  = p4 * 4;
    const int h  = p / W_;
    const int w0 = p % W_;          // multiple of 4 (28 % 4 == 0)
    float r[3][6];
    #pragma unroll
    for (int ry = 0; ry < 3; ++ry) {
        const int hh = h - 1 + ry;
        if (hh < 0 || hh >= H_) {
            #pragma unroll
            for (int j = 0; j < 6; ++j) r[ry][j] = 0.0f;
        } else {
            const float* row = xbc + hh * W_;
            f32x4 mid = *(const f32x4*)(row + w0);
            r[ry][1] = mid.x; r[ry][2] = mid.y; r[ry][3] = mid.z; r[ry][4] = mid.w;
            r[ry][0] = (w0 > 0)      ? row[w0 - 1] : 0.0f;
            r[ry][5] = (w0 + 4 < W_) ? row[w0 + 4] : 0.0f;
        }
    }
    float wv9[9];
    #pragma unroll
    for (int k = 0; k < 9; ++k) wv9[k] = wv[c * 9 + k];

    f32x4 v4;
    #pragma unroll
    for (int j = 0; j < 4; ++j) {
        float s = 0.0f;
        #pragma unroll
        for (int ky = 0; ky < 3; ++ky)
            #pragma unroll
            for (int kx = 0; kx < 3; ++kx)
                s = fmaf(r[ky][j + kx], wv9[ky * 3 + kx], s);
        v4[j] = s;
    }

    // t = 15 (new v): streaming store + init accumulator
    f32x4 acc;
    {
        const float a = att_s[h_][TPREV];
        __builtin_nontemporal_store(v4, &Vo[voq + (size_t)TPREV * CH4]);
        acc = v4 * a;
    }

    // drain: store-through + FMA
    #pragma unroll
    for (int t = 0; t < TPREV; ++t) {
        __builtin_nontemporal_store(pv[t], &Vo[voq + (size_t)t * CH4]);
        const float a = att_s[h_][t];
        acc.x = fmaf(a, pv[t].x, acc.x);
        acc.y = fmaf(a, pv[t].y, acc.y);
        acc.z = fmaf(a, pv[t].z, acc.z);
        acc.w = fmaf(a, pv[t].w, acc.w);
    }
    __builtin_nontemporal_store(acc, &((f32x4*)out)[(size_t)bc * HW4 + p4]);
}

extern "C" void kernel_launch(void* const* d_in, const int* in_sizes, int n_in,
                              void* d_out, int out_size, void* d_ws, size_t ws_size,
                              hipStream_t stream) {
    const float* x     = (const float*)d_in[0];
    const float* prevK = (const float*)d_in[1];
    const float* prevV = (const float*)d_in[2];
    const float* wq    = (const float*)d_in[3];
    const float* wk    = (const float*)d_in[4];
    const float* wv    = (const float*)d_in[5];

    float* out  = (float*)d_out;                       // [B,C,H,W]
    float* Kout = out + (size_t)B_ * C_ * HW;          // [B,TT,C]
    float* Vout = Kout + (size_t)B_ * TT * C_;         // [B,TT,C,H,W]

    float* y_ws = (float*)d_ws;                        // B*C pooled means

    pool_copy_kernel<<<POOL_BLOCKS + KCOPY_BLOCKS, 64, 0, stream>>>(x, prevK, y_ws, Kout);

    const int totalq = B_ * C_ * HW4;                  // 1,605,632 quads
    fuse_kernel<<<totalq / 256, 256, 0, stream>>>(x, prevV, prevK, y_ws, wq, wk, wv,
                                                  out, Kout, Vout);
}